// Round 1
// baseline (10038.970 us; speedup 1.0000x reference)
//
#include <hip/hip_runtime.h>
#include <stdint.h>

// ---------------- problem constants ----------------
#define EDIM   300      // hidden/embed dim
#define EPAD   304      // padded to 8*38 for recurrence dot
#define KPAD   320      // padded K for MFMA GEMMs
#define NG     1200     // 4*EDIM gates
#define NB     64       // batch
#define SENC   64       // encoder steps
#define SDEC   63       // decoder steps
#define ZHV    12016
#define DROWS  4032     // NB*SDEC
#define MPAD   4096

typedef unsigned short u16;
typedef __attribute__((ext_vector_type(8))) short bf16x8;
typedef __attribute__((ext_vector_type(4))) float f32x4;

static __device__ __forceinline__ float bf2f(uint32_t lo){ return __builtin_bit_cast(float, lo << 16); }
static __device__ __forceinline__ u16 f2bf(float f){
  uint32_t u = __builtin_bit_cast(uint32_t, f);
  return (u16)((u + 0x7fffu + ((u >> 16) & 1u)) >> 16);
}
static __device__ __forceinline__ float sigm(float x){ return 1.f/(1.f + __expf(-x)); }
static __device__ __forceinline__ float tanhf_(float x){
  x = fminf(fmaxf(x, -15.f), 15.f);
  float e = __expf(2.f*x);
  return (e - 1.f)/(e + 1.f);
}

// ---------------- zero workspace ----------------
__global__ void zero_kernel(float4* p, long n){
  long i = (long)blockIdx.x*blockDim.x + threadIdx.x;
  long st = (long)gridDim.x*blockDim.x;
  float4 z = {0.f,0.f,0.f,0.f};
  for (; i < n; i += st) p[i] = z;
}

// ---------------- weight repack: Whh (1200x300) f32 -> wave-tiled bf16 ----------------
// layout: uint4 chunk index ((g*38 + kc)*64 + jl); g = G*5 + w, j = G*300 + w*64 + jl,
// chunk holds k = kc*8 .. kc*8+7 (zero-padded past 300). Per-k-chunk a wave reads
// 64 contiguous uint4 = 1 KiB, fully coalesced, no L1 reliance.
__global__ void build_whh(const float* __restrict__ W, u16* __restrict__ out){
  int idx = blockIdx.x*blockDim.x + threadIdx.x;
  if (idx >= 20*38*64) return;
  int jl = idx & 63;
  int kc = (idx >> 6) % 38;
  int g  = (idx >> 6) / 38;
  int G = g/5, w = g - G*5;
  int jg = w*64 + jl;
  union { u16 u[8]; uint4 q; } v;
  for (int e=0;e<8;e++){
    int k = kc*8+e;
    float f = (jg < EDIM && k < EDIM) ? W[(size_t)(G*EDIM + jg)*EDIM + k] : 0.f;
    v.u[e] = f2bf(f);
  }
  ((uint4*)out)[idx] = v.q;
}

// ---------------- weight repack: (N x 300) f32 -> (Npad x 320) bf16, B^T-style operand ----------------
__global__ void build_b(const float* __restrict__ W, u16* __restrict__ out, int N){
  int idx = blockIdx.x*blockDim.x + threadIdx.x;
  if (idx >= N*EDIM) return;
  int n = idx / EDIM, k = idx - n*EDIM;
  out[(size_t)n*KPAD + k] = f2bf(W[idx]);
}

// ---------------- embeddings -> padded bf16 A operands ----------------
__global__ void embed_en(const int* __restrict__ ids, const float* __restrict__ emb, u16* __restrict__ x){
  int idx = blockIdx.x*blockDim.x + threadIdx.x;
  if (idx >= MPAD*EDIM) return;
  int r = idx / EDIM, k = idx - r*EDIM;
  x[(size_t)r*KPAD + k] = f2bf(emb[(size_t)ids[r]*EDIM + k]);
}
__global__ void embed_zh(const int* __restrict__ zh, const float* __restrict__ emb, u16* __restrict__ x){
  int idx = blockIdx.x*blockDim.x + threadIdx.x;
  if (idx >= DROWS*EDIM) return;
  int r = idx / EDIM, k = idx - r*EDIM;
  int b = r / SDEC, t = r - b*SDEC;
  x[(size_t)r*KPAD + k] = f2bf(emb[(size_t)zh[b*SENC + t]*EDIM + k]);
}

// ---------------- bf16 MFMA GEMM: C[m,n] = sum_k A[m,k]*B[n,k] (+bias[n]) ----------------
// A: (>=Mtiles*128 x 320) bf16 row-major, B: (>=Ntiles*128 x 320) bf16 row-major.
// 128x128 block tile, 4 waves 2x2, each wave 64x64 via 4x4 frags of 16x16x32.
#define LDT 40   // LDS row stride in bf16 elems (80 B) - breaks bank conflicts, keeps 16B align
__global__ __launch_bounds__(256) void gemm_nt(const u16* __restrict__ A, const u16* __restrict__ B,
                float* __restrict__ C, int ldc, int Mreal, int Nreal, const float* __restrict__ bias){
  __shared__ __align__(16) u16 As[128*LDT];
  __shared__ __align__(16) u16 Bs[128*LDT];
  int tid = threadIdx.x;
  int lane = tid & 63, wave = tid >> 6;
  int wm = wave >> 1, wn = wave & 1;
  int m0 = blockIdx.y*128, n0 = blockIdx.x*128;
  f32x4 acc[4][4];
  for (int i=0;i<4;i++) for (int j=0;j<4;j++) acc[i][j] = (f32x4){0.f,0.f,0.f,0.f};
  int r16 = lane & 15, kg = lane >> 4;
  for (int kt=0; kt<KPAD/32; kt++){
    int k0 = kt*32;
    for (int c=0;c<2;c++){
      int id = c*256 + tid;            // 0..511
      int row = id >> 2, col = id & 3; // 4 x 16B chunks per 32-k row
      *(uint4*)&As[row*LDT + col*8] = *(const uint4*)&A[(size_t)(m0+row)*KPAD + k0 + col*8];
      *(uint4*)&Bs[row*LDT + col*8] = *(const uint4*)&B[(size_t)(n0+row)*KPAD + k0 + col*8];
    }
    __syncthreads();
    bf16x8 af[4], bfr[4];
    for (int i=0;i<4;i++) af[i]  = *(const bf16x8*)&As[(wm*64 + i*16 + r16)*LDT + kg*8];
    for (int j=0;j<4;j++) bfr[j] = *(const bf16x8*)&Bs[(wn*64 + j*16 + r16)*LDT + kg*8];
    for (int i=0;i<4;i++)
      for (int j=0;j<4;j++)
        acc[i][j] = __builtin_amdgcn_mfma_f32_16x16x32_bf16(af[i], bfr[j], acc[i][j], 0, 0, 0);
    __syncthreads();
  }
  // C/D layout (m89-verified): col = lane&15, row = (lane>>4)*4 + reg
  for (int j=0;j<4;j++){
    int col = n0 + wn*64 + j*16 + r16;
    if (col >= Nreal) continue;
    float bv = bias ? bias[col] : 0.f;
    for (int i=0;i<4;i++){
      int rbase = m0 + wm*64 + i*16 + kg*4;
      for (int r=0;r<4;r++){
        int row = rbase + r;
        if (row < Mreal) C[(size_t)row*ldc + col] = acc[i][j][r] + bv;
      }
    }
  }
}

// ---------------- LSTM recurrence ----------------
// grid = 256: blockIdx = r*4 + G (row r owns 4 gate-blocks). 320 threads, thread jj<300
// computes gate G output j = G*300+jj. Gates exchanged via double-buffered global gx +
// per-row monotonic atomic counter barrier. c/h recomputed redundantly per block (cheap,
// bitwise-identical) so h never crosses blocks.
__global__ __launch_bounds__(320) void recur_kernel(
    const float* __restrict__ Xih, const u16* __restrict__ Wt,
    const float* __restrict__ bias, const float* __restrict__ h0,
    const float* __restrict__ c0, float* gx, int* counter,
    u16* seq, float* hfin, float* cfin, int steps)
{
  int r = blockIdx.x >> 2, G = blockIdx.x & 3;
  int tid = threadIdx.x;
  __shared__ __align__(16) float h_lds[EPAD];
  bool act = tid < EDIM;
  int jj = tid;
  int w = jj >> 6, jl = jj & 63;
  int g0 = G*5 + w;
  const uint4* wt4 = (const uint4*)Wt;
  int wbase = g0*38*64 + jl;
  float bj = act ? bias[G*EDIM + jj] : 0.f;
  float c_reg = act ? c0[r*EDIM + tid] : 0.f;
  if (tid < EDIM) h_lds[tid] = h0[r*EDIM + tid];
  else if (tid < EPAD) h_lds[tid] = 0.f;
  __syncthreads();
  int slice0 = G*75;
  for (int t=0; t<steps; t++){
    if (act){
      float acc = bj + Xih[(size_t)(r*steps + t)*NG + G*EDIM + jj];
      #pragma unroll 2
      for (int kc=0; kc<38; kc++){
        uint4 wv = wt4[wbase + (kc<<6)];
        float4 hA = *(const float4*)&h_lds[kc*8];
        float4 hB = *(const float4*)&h_lds[kc*8+4];
        acc += hA.x*bf2f(wv.x & 0xffffu);
        acc += hA.y*bf2f(wv.x >> 16);
        acc += hA.z*bf2f(wv.y & 0xffffu);
        acc += hA.w*bf2f(wv.y >> 16);
        acc += hB.x*bf2f(wv.z & 0xffffu);
        acc += hB.y*bf2f(wv.z >> 16);
        acc += hB.z*bf2f(wv.w & 0xffffu);
        acc += hB.w*bf2f(wv.w >> 16);
      }
      gx[(size_t)(t&1)*(NB*NG) + r*NG + G*EDIM + jj] = acc;
    }
    __threadfence();
    __syncthreads();
    if (tid == 0){
      __hip_atomic_fetch_add(&counter[r], 1, __ATOMIC_RELEASE, __HIP_MEMORY_SCOPE_AGENT);
      while (__hip_atomic_load(&counter[r], __ATOMIC_ACQUIRE, __HIP_MEMORY_SCOPE_AGENT) < 4*(t+1))
        __builtin_amdgcn_s_sleep(1);
    }
    __syncthreads();
    float hv = 0.f;
    if (act){
      float* g_ = gx + (size_t)(t&1)*(NB*NG) + r*NG;
      float gi = __hip_atomic_load(&g_[tid],          __ATOMIC_RELAXED, __HIP_MEMORY_SCOPE_AGENT);
      float gf = __hip_atomic_load(&g_[EDIM + tid],   __ATOMIC_RELAXED, __HIP_MEMORY_SCOPE_AGENT);
      float gg = __hip_atomic_load(&g_[2*EDIM + tid], __ATOMIC_RELAXED, __HIP_MEMORY_SCOPE_AGENT);
      float go = __hip_atomic_load(&g_[3*EDIM + tid], __ATOMIC_RELAXED, __HIP_MEMORY_SCOPE_AGENT);
      c_reg = sigm(gf)*c_reg + sigm(gi)*tanhf_(gg);
      hv = sigm(go)*tanhf_(c_reg);
      h_lds[tid] = hv;   // safe: all h_lds reads of this step finished before barrier
      if (tid >= slice0 && tid < slice0+75){
        if (seq) seq[(size_t)(r*steps + t)*KPAD + tid] = f2bf(hv);
        if (t == steps-1 && hfin){ hfin[r*EDIM + tid] = hv; cfin[r*EDIM + tid] = c_reg; }
      }
    }
    __syncthreads();
  }
}

// ---------------- fused log_softmax (in-place on d_out) + masked NLL ----------------
__global__ __launch_bounds__(256) void lsm_loss(float* __restrict__ out, const int* __restrict__ zh,
                                                float* __restrict__ lacc){
  int row = blockIdx.x;
  int tid = threadIdx.x;
  __shared__ float buf[ZHV];
  __shared__ float red[8];
  float* p = out + (size_t)row*ZHV;
  float m = -1e30f;
  for (int i=tid; i<ZHV; i+=256){ float v = p[i]; buf[i] = v; m = fmaxf(m, v); }
  for (int off=32; off; off>>=1) m = fmaxf(m, __shfl_xor(m, off));
  if ((tid&63)==0) red[tid>>6] = m;
  __syncthreads();
  m = fmaxf(fmaxf(red[0],red[1]), fmaxf(red[2],red[3]));
  float s = 0.f;
  for (int i=tid; i<ZHV; i+=256) s += __expf(buf[i]-m);
  for (int off=32; off; off>>=1) s += __shfl_xor(s, off);
  if ((tid&63)==0) red[4+(tid>>6)] = s;
  __syncthreads();
  s = red[4]+red[5]+red[6]+red[7];
  float lse = m + __logf(s);
  for (int i=tid; i<ZHV; i+=256) p[i] = buf[i] - lse;
  if (tid == 0){
    int b = row / SDEC, t = row - b*SDEC;
    int tgt = zh[b*SENC + t + 1];
    if (tgt != 0){
      atomicAdd(&lacc[0], -(buf[tgt] - lse));
      atomicAdd(&lacc[1], 1.0f);
    }
  }
}

__global__ void fin_loss(float* out, const float* lacc){
  out[(size_t)DROWS*ZHV] = lacc[0]/lacc[1];
}

// ---------------- host ----------------
extern "C" void kernel_launch(void* const* d_in, const int* in_sizes, int n_in,
                              void* d_out, int out_size, void* d_ws, size_t ws_size,
                              hipStream_t stream){
  const int*   en_in   = (const int*)d_in[0];
  const int*   zh_in   = (const int*)d_in[1];
  const float* en_emb  = (const float*)d_in[2];
  const float* zh_emb  = (const float*)d_in[3];
  const float* enc_Wih = (const float*)d_in[4];
  const float* enc_Whh = (const float*)d_in[5];
  const float* enc_b   = (const float*)d_in[6];
  const float* dec_Wih = (const float*)d_in[7];
  const float* dec_Whh = (const float*)d_in[8];
  const float* dec_b   = (const float*)d_in[9];
  const float* fc_W    = (const float*)d_in[10];
  const float* fc_b    = (const float*)d_in[11];
  float* out = (float*)d_out;
  char* ws = (char*)d_ws;

  size_t o = 0;
  auto alloc = [&](size_t b){ size_t r = o; o = (o + b + 255) & ~(size_t)255; return r; };
  size_t whh[4], wih[4];
  for (int i=0;i<4;i++) whh[i] = alloc((size_t)20*38*64*8*2);   // wave-tiled Whh bf16
  for (int i=0;i<4;i++) wih[i] = alloc((size_t)1280*KPAD*2);    // Wih as B operand
  size_t fcw  = alloc((size_t)12032*KPAD*2);
  size_t xen  = alloc((size_t)MPAD*KPAD*2);
  size_t xl1e = alloc((size_t)MPAD*KPAD*2);
  size_t xzh  = alloc((size_t)MPAD*KPAD*2);
  size_t xl1d = alloc((size_t)MPAD*KPAD*2);
  size_t xl2d = alloc((size_t)MPAD*KPAD*2);
  size_t xih  = alloc((size_t)MPAD*NG*4);
  size_t gxo  = alloc((size_t)2*NB*NG*4);
  size_t hfin = alloc((size_t)2*NB*EDIM*4);
  size_t cfin = alloc((size_t)2*NB*EDIM*4);
  size_t hz   = alloc((size_t)NB*EDIM*4);
  size_t cnt  = alloc(1024);
  size_t lac  = alloc(256);
  size_t used = o;
  if (ws_size < used) return;  // fail loudly (output stays poisoned)

  zero_kernel<<<2048,256,0,stream>>>((float4*)ws, (long)(used/16));

  for (int l=0;l<2;l++){
    build_whh<<<190,256,0,stream>>>(enc_Whh + (size_t)l*NG*EDIM, (u16*)(ws+whh[l]));
    build_whh<<<190,256,0,stream>>>(dec_Whh + (size_t)l*NG*EDIM, (u16*)(ws+whh[2+l]));
    build_b<<<1407,256,0,stream>>>(enc_Wih + (size_t)l*NG*EDIM, (u16*)(ws+wih[l]),   NG);
    build_b<<<1407,256,0,stream>>>(dec_Wih + (size_t)l*NG*EDIM, (u16*)(ws+wih[2+l]), NG);
  }
  build_b<<<(ZHV*EDIM+255)/256,256,0,stream>>>(fc_W, (u16*)(ws+fcw), ZHV);
  embed_en<<<(MPAD*EDIM+255)/256,256,0,stream>>>(en_in, en_emb, (u16*)(ws+xen));
  embed_zh<<<(DROWS*EDIM+255)/256,256,0,stream>>>(zh_in, zh_emb, (u16*)(ws+xzh));

  float* XIH = (float*)(ws+xih);
  float* GX  = (float*)(ws+gxo);
  int*   CNT = (int*)(ws+cnt);
  float* LAC = (float*)(ws+lac);
  float* HF  = (float*)(ws+hfin);
  float* CF  = (float*)(ws+cfin);
  float* HZ  = (float*)(ws+hz);

  // encoder layer 1
  gemm_nt<<<dim3(10,32),256,0,stream>>>((u16*)(ws+xen), (u16*)(ws+wih[0]), XIH, NG, MPAD, NG, nullptr);
  recur_kernel<<<256,320,0,stream>>>(XIH, (u16*)(ws+whh[0]), enc_b, HZ, HZ, GX, CNT, (u16*)(ws+xl1e), HF, CF, SENC);
  // encoder layer 2 (hidden sequence unused; only finals kept)
  gemm_nt<<<dim3(10,32),256,0,stream>>>((u16*)(ws+xl1e), (u16*)(ws+wih[1]), XIH, NG, MPAD, NG, nullptr);
  recur_kernel<<<256,320,0,stream>>>(XIH, (u16*)(ws+whh[1]), enc_b+NG, HZ, HZ, GX, CNT+64, nullptr, HF+NB*EDIM, CF+NB*EDIM, SENC);
  // decoder layer 1
  gemm_nt<<<dim3(10,32),256,0,stream>>>((u16*)(ws+xzh), (u16*)(ws+wih[2]), XIH, NG, MPAD, NG, nullptr);
  recur_kernel<<<256,320,0,stream>>>(XIH, (u16*)(ws+whh[2]), dec_b, HF, CF, GX, CNT+128, (u16*)(ws+xl1d), nullptr, nullptr, SDEC);
  // decoder layer 2
  gemm_nt<<<dim3(10,32),256,0,stream>>>((u16*)(ws+xl1d), (u16*)(ws+wih[3]), XIH, NG, MPAD, NG, nullptr);
  recur_kernel<<<256,320,0,stream>>>(XIH, (u16*)(ws+whh[3]), dec_b+NG, HF+NB*EDIM, CF+NB*EDIM, GX, CNT+192, (u16*)(ws+xl2d), nullptr, nullptr, SDEC);
  // FC head -> logits straight into d_out
  gemm_nt<<<dim3(94,32),256,0,stream>>>((u16*)(ws+xl2d), (u16*)(ws+fcw), out, ZHV, DROWS, ZHV, fc_b);
  // in-place log_softmax + masked NLL
  lsm_loss<<<DROWS,256,0,stream>>>(out, zh_in, LAC);
  fin_loss<<<1,1,0,stream>>>(out, LAC);
}

// Round 2
// 2313.393 us; speedup vs baseline: 4.3395x; 4.3395x over previous
//
#include <hip/hip_runtime.h>
#include <stdint.h>

// ---------------- problem constants ----------------
#define EDIM   300      // hidden/embed dim
#define EPAD   304      // padded to 8*38 for recurrence dot
#define KPAD   320      // padded K for MFMA GEMMs
#define NG     1200     // 4*EDIM gates
#define NB     64       // batch
#define SENC   64       // encoder steps
#define SDEC   63       // decoder steps
#define ZHV    12016
#define DROWS  4032     // NB*SDEC
#define MPAD   4096

typedef unsigned short u16;
typedef __attribute__((ext_vector_type(8))) short bf16x8;
typedef __attribute__((ext_vector_type(4))) float f32x4;

static __device__ __forceinline__ float bf2f(uint32_t lo){ return __builtin_bit_cast(float, lo << 16); }
static __device__ __forceinline__ u16 f2bf(float f){
  uint32_t u = __builtin_bit_cast(uint32_t, f);
  return (u16)((u + 0x7fffu + ((u >> 16) & 1u)) >> 16);
}
static __device__ __forceinline__ float sigm(float x){ return 1.f/(1.f + __expf(-x)); }
static __device__ __forceinline__ float tanhf_(float x){
  x = fminf(fmaxf(x, -15.f), 15.f);
  float e = __expf(2.f*x);
  return (e - 1.f)/(e + 1.f);
}

// ---------------- zero workspace ----------------
__global__ void zero_kernel(float4* p, long n){
  long i = (long)blockIdx.x*blockDim.x + threadIdx.x;
  long st = (long)gridDim.x*blockDim.x;
  float4 z = {0.f,0.f,0.f,0.f};
  for (; i < n; i += st) p[i] = z;
}

// ---------------- weight repack: Whh (1200x300) f32 -> wave-tiled bf16 ----------------
// layout: uint4 chunk index ((g*38 + kc)*64 + jl); g = G*5 + w, j = G*300 + w*64 + jl,
// chunk holds k = kc*8 .. kc*8+7 (zero-padded past 300). Per-k-chunk a wave reads
// 64 contiguous uint4 = 1 KiB, fully coalesced.
__global__ void build_whh(const float* __restrict__ W, u16* __restrict__ out){
  int idx = blockIdx.x*blockDim.x + threadIdx.x;
  if (idx >= 20*38*64) return;
  int jl = idx & 63;
  int kc = (idx >> 6) % 38;
  int g  = (idx >> 6) / 38;
  int G = g/5, w = g - G*5;
  int jg = w*64 + jl;
  union { u16 u[8]; uint4 q; } v;
  for (int e=0;e<8;e++){
    int k = kc*8+e;
    float f = (jg < EDIM && k < EDIM) ? W[(size_t)(G*EDIM + jg)*EDIM + k] : 0.f;
    v.u[e] = f2bf(f);
  }
  ((uint4*)out)[idx] = v.q;
}

// ---------------- weight repack: (N x 300) f32 -> (Npad x 320) bf16, B^T-style operand ----------------
__global__ void build_b(const float* __restrict__ W, u16* __restrict__ out, int N){
  int idx = blockIdx.x*blockDim.x + threadIdx.x;
  if (idx >= N*EDIM) return;
  int n = idx / EDIM, k = idx - n*EDIM;
  out[(size_t)n*KPAD + k] = f2bf(W[idx]);
}

// ---------------- embeddings -> padded bf16 A operands ----------------
__global__ void embed_en(const int* __restrict__ ids, const float* __restrict__ emb, u16* __restrict__ x){
  int idx = blockIdx.x*blockDim.x + threadIdx.x;
  if (idx >= MPAD*EDIM) return;
  int r = idx / EDIM, k = idx - r*EDIM;
  x[(size_t)r*KPAD + k] = f2bf(emb[(size_t)ids[r]*EDIM + k]);
}
__global__ void embed_zh(const int* __restrict__ zh, const float* __restrict__ emb, u16* __restrict__ x){
  int idx = blockIdx.x*blockDim.x + threadIdx.x;
  if (idx >= DROWS*EDIM) return;
  int r = idx / EDIM, k = idx - r*EDIM;
  int b = r / SDEC, t = r - b*SDEC;
  x[(size_t)r*KPAD + k] = f2bf(emb[(size_t)zh[b*SENC + t]*EDIM + k]);
}

// ---------------- bf16 MFMA GEMM: C[m,n] = sum_k A[m,k]*B[n,k] (+bias[n]) ----------------
#define LDT 40   // LDS row stride in bf16 elems (80 B)
__global__ __launch_bounds__(256) void gemm_nt(const u16* __restrict__ A, const u16* __restrict__ B,
                float* __restrict__ C, int ldc, int Mreal, int Nreal, const float* __restrict__ bias){
  __shared__ __align__(16) u16 As[128*LDT];
  __shared__ __align__(16) u16 Bs[128*LDT];
  int tid = threadIdx.x;
  int lane = tid & 63, wave = tid >> 6;
  int wm = wave >> 1, wn = wave & 1;
  int m0 = blockIdx.y*128, n0 = blockIdx.x*128;
  f32x4 acc[4][4];
  for (int i=0;i<4;i++) for (int j=0;j<4;j++) acc[i][j] = (f32x4){0.f,0.f,0.f,0.f};
  int r16 = lane & 15, kg = lane >> 4;
  for (int kt=0; kt<KPAD/32; kt++){
    int k0 = kt*32;
    for (int c=0;c<2;c++){
      int id = c*256 + tid;            // 0..511
      int row = id >> 2, col = id & 3; // 4 x 16B chunks per 32-k row
      *(uint4*)&As[row*LDT + col*8] = *(const uint4*)&A[(size_t)(m0+row)*KPAD + k0 + col*8];
      *(uint4*)&Bs[row*LDT + col*8] = *(const uint4*)&B[(size_t)(n0+row)*KPAD + k0 + col*8];
    }
    __syncthreads();
    bf16x8 af[4], bfr[4];
    for (int i=0;i<4;i++) af[i]  = *(const bf16x8*)&As[(wm*64 + i*16 + r16)*LDT + kg*8];
    for (int j=0;j<4;j++) bfr[j] = *(const bf16x8*)&Bs[(wn*64 + j*16 + r16)*LDT + kg*8];
    for (int i=0;i<4;i++)
      for (int j=0;j<4;j++)
        acc[i][j] = __builtin_amdgcn_mfma_f32_16x16x32_bf16(af[i], bfr[j], acc[i][j], 0, 0, 0);
    __syncthreads();
  }
  // C/D layout (m89-verified): col = lane&15, row = (lane>>4)*4 + reg
  for (int j=0;j<4;j++){
    int col = n0 + wn*64 + j*16 + r16;
    if (col >= Nreal) continue;
    float bv = bias ? bias[col] : 0.f;
    for (int i=0;i<4;i++){
      int rbase = m0 + wm*64 + i*16 + kg*4;
      for (int r=0;r<4;r++){
        int row = rbase + r;
        if (row < Mreal) C[(size_t)row*ldc + col] = acc[i][j][r] + bv;
      }
    }
  }
}

// ---------------- LSTM recurrence ----------------
// grid = 256: blockIdx = r*4 + G (row r owns 4 gate-blocks). Fence-free message
// passing: gate values stored with device-scope RELAXED atomic stores (write-through
// to the coherence point), __syncthreads() drains vmcnt(0) for ALL lanes before
// tid0 bumps the per-row monotonic counter (padded to 256B to kill line contention).
// Readers use device-scope RELAXED atomic loads -> always fresh, no cache fences.
__global__ __launch_bounds__(320) void recur_kernel(
    const float* __restrict__ Xih, const u16* __restrict__ Wt,
    const float* __restrict__ bias, const float* __restrict__ h0,
    const float* __restrict__ c0, float* gx, int* counter,
    u16* seq, float* hfin, float* cfin, int steps)
{
  int r = blockIdx.x >> 2, G = blockIdx.x & 3;
  int tid = threadIdx.x;
  __shared__ __align__(16) float h_lds[EPAD];
  bool act = tid < EDIM;
  int jj = tid;
  int w = jj >> 6, jl = jj & 63;
  int g0 = G*5 + w;
  const uint4* wt4 = (const uint4*)Wt;
  int wbase = g0*38*64 + jl;
  int* cc = &counter[r << 6];     // 256B-padded per-row counter
  float bj = act ? bias[G*EDIM + jj] : 0.f;
  float c_reg = act ? c0[r*EDIM + tid] : 0.f;
  if (tid < EDIM) h_lds[tid] = h0[r*EDIM + tid];
  else if (tid < EPAD) h_lds[tid] = 0.f;
  __syncthreads();
  int slice0 = G*75;
  for (int t=0; t<steps; t++){
    if (act){
      float xv = Xih[(size_t)(r*steps + t)*NG + G*EDIM + jj];
      float a0=0.f, a1=0.f, a2=0.f, a3=0.f;   // 4 independent FMA chains
      #pragma unroll
      for (int kc=0; kc<38; kc++){
        uint4 wv = wt4[wbase + (kc<<6)];
        float4 hA = *(const float4*)&h_lds[kc*8];
        float4 hB = *(const float4*)&h_lds[kc*8+4];
        a0 += hA.x*bf2f(wv.x & 0xffffu) + hB.x*bf2f(wv.z & 0xffffu);
        a1 += hA.y*bf2f(wv.x >> 16)     + hB.y*bf2f(wv.z >> 16);
        a2 += hA.z*bf2f(wv.y & 0xffffu) + hB.z*bf2f(wv.w & 0xffffu);
        a3 += hA.w*bf2f(wv.y >> 16)     + hB.w*bf2f(wv.w >> 16);
      }
      float acc = bj + xv + ((a0+a1) + (a2+a3));
      __hip_atomic_store(&gx[(size_t)(t&1)*(NB*NG) + r*NG + G*EDIM + jj], acc,
                         __ATOMIC_RELAXED, __HIP_MEMORY_SCOPE_AGENT);
    }
    __syncthreads();   // drains vmcnt(0) for every lane -> all gate stores at LLC
    if (tid == 0){
      __hip_atomic_fetch_add(cc, 1, __ATOMIC_RELEASE, __HIP_MEMORY_SCOPE_AGENT);
      while (__hip_atomic_load(cc, __ATOMIC_RELAXED, __HIP_MEMORY_SCOPE_AGENT) < 4*(t+1))
        __builtin_amdgcn_s_sleep(1);
    }
    __syncthreads();
    float hv = 0.f;
    if (act){
      float* g_ = gx + (size_t)(t&1)*(NB*NG) + r*NG;
      float gi = __hip_atomic_load(&g_[tid],          __ATOMIC_RELAXED, __HIP_MEMORY_SCOPE_AGENT);
      float gf = __hip_atomic_load(&g_[EDIM + tid],   __ATOMIC_RELAXED, __HIP_MEMORY_SCOPE_AGENT);
      float gg = __hip_atomic_load(&g_[2*EDIM + tid], __ATOMIC_RELAXED, __HIP_MEMORY_SCOPE_AGENT);
      float go = __hip_atomic_load(&g_[3*EDIM + tid], __ATOMIC_RELAXED, __HIP_MEMORY_SCOPE_AGENT);
      c_reg = sigm(gf)*c_reg + sigm(gi)*tanhf_(gg);
      hv = sigm(go)*tanhf_(c_reg);
      h_lds[tid] = hv;   // safe: all h_lds reads of this step finished before barrier
      if (tid >= slice0 && tid < slice0+75){
        if (seq) seq[(size_t)(r*steps + t)*KPAD + tid] = f2bf(hv);
        if (t == steps-1 && hfin){ hfin[r*EDIM + tid] = hv; cfin[r*EDIM + tid] = c_reg; }
      }
    }
    __syncthreads();
  }
}

// ---------------- fused log_softmax (in-place on d_out) + masked NLL ----------------
__global__ __launch_bounds__(256) void lsm_loss(float* __restrict__ out, const int* __restrict__ zh,
                                                float* __restrict__ lacc){
  int row = blockIdx.x;
  int tid = threadIdx.x;
  __shared__ float buf[ZHV];
  __shared__ float red[8];
  float* p = out + (size_t)row*ZHV;
  float m = -1e30f;
  for (int i=tid; i<ZHV; i+=256){ float v = p[i]; buf[i] = v; m = fmaxf(m, v); }
  for (int off=32; off; off>>=1) m = fmaxf(m, __shfl_xor(m, off));
  if ((tid&63)==0) red[tid>>6] = m;
  __syncthreads();
  m = fmaxf(fmaxf(red[0],red[1]), fmaxf(red[2],red[3]));
  float s = 0.f;
  for (int i=tid; i<ZHV; i+=256) s += __expf(buf[i]-m);
  for (int off=32; off; off>>=1) s += __shfl_xor(s, off);
  if ((tid&63)==0) red[4+(tid>>6)] = s;
  __syncthreads();
  s = red[4]+red[5]+red[6]+red[7];
  float lse = m + __logf(s);
  for (int i=tid; i<ZHV; i+=256) p[i] = buf[i] - lse;
  if (tid == 0){
    int b = row / SDEC, t = row - b*SDEC;
    int tgt = zh[b*SENC + t + 1];
    if (tgt != 0){
      atomicAdd(&lacc[0], -(buf[tgt] - lse));
      atomicAdd(&lacc[1], 1.0f);
    }
  }
}

__global__ void fin_loss(float* out, const float* lacc){
  out[(size_t)DROWS*ZHV] = lacc[0]/lacc[1];
}

// ---------------- host ----------------
extern "C" void kernel_launch(void* const* d_in, const int* in_sizes, int n_in,
                              void* d_out, int out_size, void* d_ws, size_t ws_size,
                              hipStream_t stream){
  const int*   en_in   = (const int*)d_in[0];
  const int*   zh_in   = (const int*)d_in[1];
  const float* en_emb  = (const float*)d_in[2];
  const float* zh_emb  = (const float*)d_in[3];
  const float* enc_Wih = (const float*)d_in[4];
  const float* enc_Whh = (const float*)d_in[5];
  const float* enc_b   = (const float*)d_in[6];
  const float* dec_Wih = (const float*)d_in[7];
  const float* dec_Whh = (const float*)d_in[8];
  const float* dec_b   = (const float*)d_in[9];
  const float* fc_W    = (const float*)d_in[10];
  const float* fc_b    = (const float*)d_in[11];
  float* out = (float*)d_out;
  char* ws = (char*)d_ws;

  size_t o = 0;
  auto alloc = [&](size_t b){ size_t r = o; o = (o + b + 255) & ~(size_t)255; return r; };
  size_t whh[4], wih[4];
  for (int i=0;i<4;i++) whh[i] = alloc((size_t)20*38*64*8*2);   // wave-tiled Whh bf16
  for (int i=0;i<4;i++) wih[i] = alloc((size_t)1280*KPAD*2);    // Wih as B operand
  size_t fcw  = alloc((size_t)12032*KPAD*2);
  size_t xen  = alloc((size_t)MPAD*KPAD*2);
  size_t xl1e = alloc((size_t)MPAD*KPAD*2);
  size_t xzh  = alloc((size_t)MPAD*KPAD*2);
  size_t xl1d = alloc((size_t)MPAD*KPAD*2);
  size_t xl2d = alloc((size_t)MPAD*KPAD*2);
  size_t xih  = alloc((size_t)MPAD*NG*4);
  size_t gxo  = alloc((size_t)2*NB*NG*4);
  size_t hfin = alloc((size_t)2*NB*EDIM*4);
  size_t cfin = alloc((size_t)2*NB*EDIM*4);
  size_t hz   = alloc((size_t)NB*EDIM*4);
  size_t cnt  = alloc((size_t)4*64*256);   // 4 layers x 64 rows x 256B-padded counters
  size_t lac  = alloc(256);
  size_t used = o;
  if (ws_size < used) return;  // fail loudly (output stays poisoned)

  zero_kernel<<<2048,256,0,stream>>>((float4*)ws, (long)(used/16));

  for (int l=0;l<2;l++){
    build_whh<<<190,256,0,stream>>>(enc_Whh + (size_t)l*NG*EDIM, (u16*)(ws+whh[l]));
    build_whh<<<190,256,0,stream>>>(dec_Whh + (size_t)l*NG*EDIM, (u16*)(ws+whh[2+l]));
    build_b<<<1407,256,0,stream>>>(enc_Wih + (size_t)l*NG*EDIM, (u16*)(ws+wih[l]),   NG);
    build_b<<<1407,256,0,stream>>>(dec_Wih + (size_t)l*NG*EDIM, (u16*)(ws+wih[2+l]), NG);
  }
  build_b<<<(ZHV*EDIM+255)/256,256,0,stream>>>(fc_W, (u16*)(ws+fcw), ZHV);
  embed_en<<<(MPAD*EDIM+255)/256,256,0,stream>>>(en_in, en_emb, (u16*)(ws+xen));
  embed_zh<<<(DROWS*EDIM+255)/256,256,0,stream>>>(zh_in, zh_emb, (u16*)(ws+xzh));

  float* XIH = (float*)(ws+xih);
  float* GX  = (float*)(ws+gxo);
  int*   CNT = (int*)(ws+cnt);
  float* LAC = (float*)(ws+lac);
  float* HF  = (float*)(ws+hfin);
  float* CF  = (float*)(ws+cfin);
  float* HZ  = (float*)(ws+hz);

  // encoder layer 1
  gemm_nt<<<dim3(10,32),256,0,stream>>>((u16*)(ws+xen), (u16*)(ws+wih[0]), XIH, NG, MPAD, NG, nullptr);
  recur_kernel<<<256,320,0,stream>>>(XIH, (u16*)(ws+whh[0]), enc_b, HZ, HZ, GX, CNT, (u16*)(ws+xl1e), HF, CF, SENC);
  // encoder layer 2 (hidden sequence unused; only finals kept)
  gemm_nt<<<dim3(10,32),256,0,stream>>>((u16*)(ws+xl1e), (u16*)(ws+wih[1]), XIH, NG, MPAD, NG, nullptr);
  recur_kernel<<<256,320,0,stream>>>(XIH, (u16*)(ws+whh[1]), enc_b+NG, HZ, HZ, GX, CNT+64*64, nullptr, HF+NB*EDIM, CF+NB*EDIM, SENC);
  // decoder layer 1
  gemm_nt<<<dim3(10,32),256,0,stream>>>((u16*)(ws+xzh), (u16*)(ws+wih[2]), XIH, NG, MPAD, NG, nullptr);
  recur_kernel<<<256,320,0,stream>>>(XIH, (u16*)(ws+whh[2]), dec_b, HF, CF, GX, CNT+2*64*64, (u16*)(ws+xl1d), nullptr, nullptr, SDEC);
  // decoder layer 2
  gemm_nt<<<dim3(10,32),256,0,stream>>>((u16*)(ws+xl1d), (u16*)(ws+wih[3]), XIH, NG, MPAD, NG, nullptr);
  recur_kernel<<<256,320,0,stream>>>(XIH, (u16*)(ws+whh[3]), dec_b+NG, HF+NB*EDIM, CF+NB*EDIM, GX, CNT+3*64*64, (u16*)(ws+xl2d), nullptr, nullptr, SDEC);
  // FC head -> logits straight into d_out
  gemm_nt<<<dim3(94,32),256,0,stream>>>((u16*)(ws+xl2d), (u16*)(ws+fcw), out, ZHV, DROWS, ZHV, fc_b);
  // in-place log_softmax + masked NLL
  lsm_loss<<<DROWS,256,0,stream>>>(out, zh_in, LAC);
  fin_loss<<<1,1,0,stream>>>(out, LAC);
}

// Round 3
// 1727.568 us; speedup vs baseline: 5.8110x; 1.3391x over previous
//
#include <hip/hip_runtime.h>
#include <stdint.h>

// ---------------- problem constants ----------------
#define EDIM   300      // hidden/embed dim
#define EPAD   304      // padded to 8*38 for recurrence dot
#define KPAD   320      // padded K for MFMA GEMMs
#define NG     1200     // 4*EDIM gates
#define NB     64       // batch
#define SENC   64       // encoder steps
#define SDEC   63       // decoder steps
#define ZHV    12016
#define DROWS  4032     // NB*SDEC
#define MPAD   4096
#define SENT   0xFFC0ACDCu   // impossible-from-finite-math NaN bit pattern
#define GSLOT  (NB*NG)       // floats per gate-exchange slot

typedef unsigned short u16;
typedef __attribute__((ext_vector_type(8))) short bf16x8;
typedef __attribute__((ext_vector_type(4))) float f32x4;

static __device__ __forceinline__ float bflo(uint32_t u){ return __builtin_bit_cast(float, u << 16); }
static __device__ __forceinline__ float bfhi(uint32_t u){ return __builtin_bit_cast(float, u & 0xffff0000u); }
static __device__ __forceinline__ u16 f2bf(float f){
  uint32_t u = __builtin_bit_cast(uint32_t, f);
  return (u16)((u + 0x7fffu + ((u >> 16) & 1u)) >> 16);
}
static __device__ __forceinline__ float sigm(float x){ return 1.f/(1.f + __expf(-x)); }
static __device__ __forceinline__ float tanhf_(float x){
  x = fminf(fmaxf(x, -15.f), 15.f);
  float e = __expf(2.f*x);
  return (e - 1.f)/(e + 1.f);
}

// ---------------- workspace init ----------------
__global__ void zero_kernel(float4* p, long n){
  long i = (long)blockIdx.x*blockDim.x + threadIdx.x;
  long st = (long)gridDim.x*blockDim.x;
  float4 z = {0.f,0.f,0.f,0.f};
  for (; i < n; i += st) p[i] = z;
}
__global__ void fill_sent(uint32_t* p, long n){
  long i = (long)blockIdx.x*blockDim.x + threadIdx.x;
  long st = (long)gridDim.x*blockDim.x;
  for (; i < n; i += st) p[i] = SENT;
}

// ---------------- weight repack: Whh (1200x300) f32 -> wave-tiled bf16 ----------------
// uint4 chunk index ((g*38 + kc)*64 + jl); g = G*5 + w, j = G*300 + w*64 + jl,
// chunk holds k = kc*8 .. kc*8+7 (zero-padded past 300).
__global__ void build_whh(const float* __restrict__ W, u16* __restrict__ out){
  int idx = blockIdx.x*blockDim.x + threadIdx.x;
  if (idx >= 20*38*64) return;
  int jl = idx & 63;
  int kc = (idx >> 6) % 38;
  int g  = (idx >> 6) / 38;
  int G = g/5, w = g - G*5;
  int jg = w*64 + jl;
  union { u16 u[8]; uint4 q; } v;
  for (int e=0;e<8;e++){
    int k = kc*8+e;
    float f = (jg < EDIM && k < EDIM) ? W[(size_t)(G*EDIM + jg)*EDIM + k] : 0.f;
    v.u[e] = f2bf(f);
  }
  ((uint4*)out)[idx] = v.q;
}

// ---------------- weight repack: (N x 300) f32 -> (Npad x 320) bf16 ----------------
__global__ void build_b(const float* __restrict__ W, u16* __restrict__ out, int N){
  int idx = blockIdx.x*blockDim.x + threadIdx.x;
  if (idx >= N*EDIM) return;
  int n = idx / EDIM, k = idx - n*EDIM;
  out[(size_t)n*KPAD + k] = f2bf(W[idx]);
}

// ---------------- embeddings -> padded bf16 A operands ----------------
__global__ void embed_en(const int* __restrict__ ids, const float* __restrict__ emb, u16* __restrict__ x){
  int idx = blockIdx.x*blockDim.x + threadIdx.x;
  if (idx >= MPAD*EDIM) return;
  int r = idx / EDIM, k = idx - r*EDIM;
  x[(size_t)r*KPAD + k] = f2bf(emb[(size_t)ids[r]*EDIM + k]);
}
__global__ void embed_zh(const int* __restrict__ zh, const float* __restrict__ emb, u16* __restrict__ x){
  int idx = blockIdx.x*blockDim.x + threadIdx.x;
  if (idx >= DROWS*EDIM) return;
  int r = idx / EDIM, k = idx - r*EDIM;
  int b = r / SDEC, t = r - b*SDEC;
  x[(size_t)r*KPAD + k] = f2bf(emb[(size_t)zh[b*SENC + t]*EDIM + k]);
}

// ---------------- bf16 MFMA GEMM: C[m,n] = sum_k A[m,k]*B[n,k] (+bias[n]) ----------------
#define LDT 40   // LDS row stride in bf16 elems (80 B)
__global__ __launch_bounds__(256) void gemm_nt(const u16* __restrict__ A, const u16* __restrict__ B,
                float* __restrict__ C, int ldc, int Mreal, int Nreal, const float* __restrict__ bias){
  __shared__ __align__(16) u16 As[128*LDT];
  __shared__ __align__(16) u16 Bs[128*LDT];
  int tid = threadIdx.x;
  int lane = tid & 63, wave = tid >> 6;
  int wm = wave >> 1, wn = wave & 1;
  int m0 = blockIdx.y*128, n0 = blockIdx.x*128;
  f32x4 acc[4][4];
  for (int i=0;i<4;i++) for (int j=0;j<4;j++) acc[i][j] = (f32x4){0.f,0.f,0.f,0.f};
  int r16 = lane & 15, kg = lane >> 4;
  for (int kt=0; kt<KPAD/32; kt++){
    int k0 = kt*32;
    for (int c=0;c<2;c++){
      int id = c*256 + tid;            // 0..511
      int row = id >> 2, col = id & 3; // 4 x 16B chunks per 32-k row
      *(uint4*)&As[row*LDT + col*8] = *(const uint4*)&A[(size_t)(m0+row)*KPAD + k0 + col*8];
      *(uint4*)&Bs[row*LDT + col*8] = *(const uint4*)&B[(size_t)(n0+row)*KPAD + k0 + col*8];
    }
    __syncthreads();
    bf16x8 af[4], bfr[4];
    for (int i=0;i<4;i++) af[i]  = *(const bf16x8*)&As[(wm*64 + i*16 + r16)*LDT + kg*8];
    for (int j=0;j<4;j++) bfr[j] = *(const bf16x8*)&Bs[(wn*64 + j*16 + r16)*LDT + kg*8];
    for (int i=0;i<4;i++)
      for (int j=0;j<4;j++)
        acc[i][j] = __builtin_amdgcn_mfma_f32_16x16x32_bf16(af[i], bfr[j], acc[i][j], 0, 0, 0);
    __syncthreads();
  }
  // C/D layout (m89-verified): col = lane&15, row = (lane>>4)*4 + reg
  for (int j=0;j<4;j++){
    int col = n0 + wn*64 + j*16 + r16;
    if (col >= Nreal) continue;
    float bv = bias ? bias[col] : 0.f;
    for (int i=0;i<4;i++){
      int rbase = m0 + wm*64 + i*16 + kg*4;
      for (int r=0;r<4;r++){
        int row = rbase + r;
        if (row < Mreal) C[(size_t)row*ldc + col] = acc[i][j][r] + bv;
      }
    }
  }
}

// ---------------- LSTM recurrence ----------------
// grid = 256: blockIdx = r*4 + G. Counter-free data-polling protocol:
//   producers store gates with relaxed agent-scope stores into slot (t&3);
//   consumers spin on their 4 gate values against the SENT NaN bit pattern
//   (the store IS the ready signal -> 1 LLC round trip, no fences, no RMW).
// Slot recycling (depth 4): at step t, after the poll succeeds, each thread
// resets ITS OWN produced word in slot (t+2)&3 (holding step t-2 data).
// Safety: reaching step-t poll-success implies every block produced step t,
// hence consumed t-1, hence all consumed t-2 -> nobody reads t-2 again. The
// reset is ordered before the same thread's t+2 data store by the barriers'
// vmcnt(0) drains, and lands before consumers poll t+2 (they poll only after
// consuming t+1, which postdates this block's t+1 production, which postdates
// the reset in program order).
__global__ __launch_bounds__(320) void recur_kernel(
    const float* __restrict__ Xih, const u16* __restrict__ Wt,
    const float* __restrict__ bias, const float* __restrict__ h0,
    const float* __restrict__ c0, float* gx,
    u16* seq, float* hfin, float* cfin, int steps)
{
  int r = blockIdx.x >> 2, G = blockIdx.x & 3;
  int tid = threadIdx.x;
  __shared__ __align__(16) float h_lds[EPAD];
  bool act = tid < EDIM;
  int jj = tid;
  int w = jj >> 6, jl = jj & 63;
  int g0 = G*5 + w;
  const uint4* wt4 = (const uint4*)Wt;
  int wbase = g0*38*64 + jl;
  float bj = act ? bias[G*EDIM + jj] : 0.f;
  float c_reg = act ? c0[r*EDIM + tid] : 0.f;
  if (tid < EDIM) h_lds[tid] = h0[r*EDIM + tid];
  else if (tid < EPAD) h_lds[tid] = 0.f;
  __syncthreads();
  int slice0 = G*75;
  for (int t=0; t<steps; t++){
    if (act){
      float xv = Xih[(size_t)(r*steps + t)*NG + G*EDIM + jj];
      float a0=0.f, a1=0.f, a2=0.f, a3=0.f;   // 4 independent FMA chains
      #pragma unroll
      for (int kc=0; kc<38; kc++){
        uint4 wv = wt4[wbase + (kc<<6)];
        float4 hA = *(const float4*)&h_lds[kc*8];
        float4 hB = *(const float4*)&h_lds[kc*8+4];
        a0 += hA.x*bflo(wv.x); a1 += hA.y*bfhi(wv.x);
        a2 += hA.z*bflo(wv.y); a3 += hA.w*bfhi(wv.y);
        a0 += hB.x*bflo(wv.z); a1 += hB.y*bfhi(wv.z);
        a2 += hB.z*bflo(wv.w); a3 += hB.w*bfhi(wv.w);
      }
      float acc = bj + xv + ((a0+a1) + (a2+a3));
      __hip_atomic_store(&gx[(size_t)(t&3)*GSLOT + r*NG + G*EDIM + jj], acc,
                         __ATOMIC_RELAXED, __HIP_MEMORY_SCOPE_AGENT);
    }
    __syncthreads();   // all h_lds dot-reads done; gate stores drained (vmcnt 0)
    float hv = 0.f;
    if (act){
      const float* g_ = gx + (size_t)(t&3)*GSLOT + r*NG;
      float gi, gf, gg, go;
      for (;;){
        gi = __hip_atomic_load(&g_[tid],          __ATOMIC_RELAXED, __HIP_MEMORY_SCOPE_AGENT);
        gf = __hip_atomic_load(&g_[EDIM + tid],   __ATOMIC_RELAXED, __HIP_MEMORY_SCOPE_AGENT);
        gg = __hip_atomic_load(&g_[2*EDIM + tid], __ATOMIC_RELAXED, __HIP_MEMORY_SCOPE_AGENT);
        go = __hip_atomic_load(&g_[3*EDIM + tid], __ATOMIC_RELAXED, __HIP_MEMORY_SCOPE_AGENT);
        uint32_t ui = __builtin_bit_cast(uint32_t, gi), uf = __builtin_bit_cast(uint32_t, gf);
        uint32_t ug = __builtin_bit_cast(uint32_t, gg), uo = __builtin_bit_cast(uint32_t, go);
        if (ui != SENT && uf != SENT && ug != SENT && uo != SENT) break;
        __builtin_amdgcn_s_sleep(1);
      }
      // recycle: clear our produced word of the slot holding step t-2 data
      __hip_atomic_store((uint32_t*)&gx[(size_t)((t+2)&3)*GSLOT + r*NG + G*EDIM + jj], SENT,
                         __ATOMIC_RELAXED, __HIP_MEMORY_SCOPE_AGENT);
      c_reg = sigm(gf)*c_reg + sigm(gi)*tanhf_(gg);
      hv = sigm(go)*tanhf_(c_reg);
      h_lds[tid] = hv;   // safe: every thread passed the barrier after its dot
      if (tid >= slice0 && tid < slice0+75){
        if (seq) seq[(size_t)(r*steps + t)*KPAD + tid] = f2bf(hv);
        if (t == steps-1 && hfin){ hfin[r*EDIM + tid] = hv; cfin[r*EDIM + tid] = c_reg; }
      }
    }
    __syncthreads();   // h(t) complete before next dot
  }
}

// ---------------- fused log_softmax (in-place on d_out) + masked NLL ----------------
__global__ __launch_bounds__(256) void lsm_loss(float* __restrict__ out, const int* __restrict__ zh,
                                                float* __restrict__ lacc){
  int row = blockIdx.x;
  int tid = threadIdx.x;
  __shared__ float buf[ZHV];
  __shared__ float red[8];
  float* p = out + (size_t)row*ZHV;
  float m = -1e30f;
  for (int i=tid; i<ZHV; i+=256){ float v = p[i]; buf[i] = v; m = fmaxf(m, v); }
  for (int off=32; off; off>>=1) m = fmaxf(m, __shfl_xor(m, off));
  if ((tid&63)==0) red[tid>>6] = m;
  __syncthreads();
  m = fmaxf(fmaxf(red[0],red[1]), fmaxf(red[2],red[3]));
  float s = 0.f;
  for (int i=tid; i<ZHV; i+=256) s += __expf(buf[i]-m);
  for (int off=32; off; off>>=1) s += __shfl_xor(s, off);
  if ((tid&63)==0) red[4+(tid>>6)] = s;
  __syncthreads();
  s = red[4]+red[5]+red[6]+red[7];
  float lse = m + __logf(s);
  for (int i=tid; i<ZHV; i+=256) p[i] = buf[i] - lse;
  if (tid == 0){
    int b = row / SDEC, t = row - b*SDEC;
    int tgt = zh[b*SENC + t + 1];
    if (tgt != 0){
      atomicAdd(&lacc[0], -(buf[tgt] - lse));
      atomicAdd(&lacc[1], 1.0f);
    }
  }
}

__global__ void fin_loss(float* out, const float* lacc){
  out[(size_t)DROWS*ZHV] = lacc[0]/lacc[1];
}

// ---------------- host ----------------
extern "C" void kernel_launch(void* const* d_in, const int* in_sizes, int n_in,
                              void* d_out, int out_size, void* d_ws, size_t ws_size,
                              hipStream_t stream){
  const int*   en_in   = (const int*)d_in[0];
  const int*   zh_in   = (const int*)d_in[1];
  const float* en_emb  = (const float*)d_in[2];
  const float* zh_emb  = (const float*)d_in[3];
  const float* enc_Wih = (const float*)d_in[4];
  const float* enc_Whh = (const float*)d_in[5];
  const float* enc_b   = (const float*)d_in[6];
  const float* dec_Wih = (const float*)d_in[7];
  const float* dec_Whh = (const float*)d_in[8];
  const float* dec_b   = (const float*)d_in[9];
  const float* fc_W    = (const float*)d_in[10];
  const float* fc_b    = (const float*)d_in[11];
  float* out = (float*)d_out;
  char* ws = (char*)d_ws;

  size_t o = 0;
  auto alloc = [&](size_t b){ size_t r = o; o = (o + b + 255) & ~(size_t)255; return r; };
  size_t whh[4], wih[4];
  for (int i=0;i<4;i++) whh[i] = alloc((size_t)20*38*64*8*2);   // wave-tiled Whh bf16
  for (int i=0;i<4;i++) wih[i] = alloc((size_t)1280*KPAD*2);    // Wih as B operand
  size_t fcw  = alloc((size_t)12032*KPAD*2);
  size_t xen  = alloc((size_t)MPAD*KPAD*2);
  size_t xl1e = alloc((size_t)MPAD*KPAD*2);
  size_t xzh  = alloc((size_t)MPAD*KPAD*2);
  size_t xl1d = alloc((size_t)MPAD*KPAD*2);
  size_t xl2d = alloc((size_t)MPAD*KPAD*2);
  size_t xih  = alloc((size_t)MPAD*NG*4);
  size_t gxo  = alloc((size_t)4*4*GSLOT*4);   // 4 layers x 4 slots, sentinel-filled
  size_t hfin = alloc((size_t)2*NB*EDIM*4);
  size_t cfin = alloc((size_t)2*NB*EDIM*4);
  size_t hz   = alloc((size_t)NB*EDIM*4);
  size_t lac  = alloc(256);
  size_t used = o;
  if (ws_size < used) return;  // fail loudly (output stays poisoned)

  zero_kernel<<<2048,256,0,stream>>>((float4*)ws, (long)(used/16));
  fill_sent<<<1024,256,0,stream>>>((uint32_t*)(ws+gxo), (long)4*4*GSLOT);

  for (int l=0;l<2;l++){
    build_whh<<<190,256,0,stream>>>(enc_Whh + (size_t)l*NG*EDIM, (u16*)(ws+whh[l]));
    build_whh<<<190,256,0,stream>>>(dec_Whh + (size_t)l*NG*EDIM, (u16*)(ws+whh[2+l]));
    build_b<<<1407,256,0,stream>>>(enc_Wih + (size_t)l*NG*EDIM, (u16*)(ws+wih[l]),   NG);
    build_b<<<1407,256,0,stream>>>(dec_Wih + (size_t)l*NG*EDIM, (u16*)(ws+wih[2+l]), NG);
  }
  build_b<<<(ZHV*EDIM+255)/256,256,0,stream>>>(fc_W, (u16*)(ws+fcw), ZHV);
  embed_en<<<(MPAD*EDIM+255)/256,256,0,stream>>>(en_in, en_emb, (u16*)(ws+xen));
  embed_zh<<<(DROWS*EDIM+255)/256,256,0,stream>>>(zh_in, zh_emb, (u16*)(ws+xzh));

  float* XIH = (float*)(ws+xih);
  float* GX  = (float*)(ws+gxo);
  float* LAC = (float*)(ws+lac);
  float* HF  = (float*)(ws+hfin);
  float* CF  = (float*)(ws+cfin);
  float* HZ  = (float*)(ws+hz);

  // encoder layer 1
  gemm_nt<<<dim3(10,32),256,0,stream>>>((u16*)(ws+xen), (u16*)(ws+wih[0]), XIH, NG, MPAD, NG, nullptr);
  recur_kernel<<<256,320,0,stream>>>(XIH, (u16*)(ws+whh[0]), enc_b, HZ, HZ, GX, (u16*)(ws+xl1e), HF, CF, SENC);
  // encoder layer 2 (hidden sequence unused; only finals kept)
  gemm_nt<<<dim3(10,32),256,0,stream>>>((u16*)(ws+xl1e), (u16*)(ws+wih[1]), XIH, NG, MPAD, NG, nullptr);
  recur_kernel<<<256,320,0,stream>>>(XIH, (u16*)(ws+whh[1]), enc_b+NG, HZ, HZ, GX+(size_t)4*GSLOT, nullptr, HF+NB*EDIM, CF+NB*EDIM, SENC);
  // decoder layer 1
  gemm_nt<<<dim3(10,32),256,0,stream>>>((u16*)(ws+xzh), (u16*)(ws+wih[2]), XIH, NG, MPAD, NG, nullptr);
  recur_kernel<<<256,320,0,stream>>>(XIH, (u16*)(ws+whh[2]), dec_b, HF, CF, GX+(size_t)8*GSLOT, (u16*)(ws+xl1d), nullptr, nullptr, SDEC);
  // decoder layer 2
  gemm_nt<<<dim3(10,32),256,0,stream>>>((u16*)(ws+xl1d), (u16*)(ws+wih[3]), XIH, NG, MPAD, NG, nullptr);
  recur_kernel<<<256,320,0,stream>>>(XIH, (u16*)(ws+whh[3]), dec_b+NG, HF+NB*EDIM, CF+NB*EDIM, GX+(size_t)12*GSLOT, (u16*)(ws+xl2d), nullptr, nullptr, SDEC);
  // FC head -> logits straight into d_out
  gemm_nt<<<dim3(94,32),256,0,stream>>>((u16*)(ws+xl2d), (u16*)(ws+fcw), out, ZHV, DROWS, ZHV, fc_b);
  // in-place log_softmax + masked NLL
  lsm_loss<<<DROWS,256,0,stream>>>(out, zh_in, LAC);
  fin_loss<<<1,1,0,stream>>>(out, LAC);
}